// Round 1
// baseline (487.110 us; speedup 1.0000x reference)
//
#include <hip/hip_runtime.h>
#include <hip/hip_bf16.h>
#include <math.h>

#define NSLICE 2048
#define NH 133     // output spatial size (int(128*1+4)+1)
#define NP 144     // padded to multiple of 16

// ---------------------------------------------------------------------------
// prep_M: build the two combined transform matrices in workspace.
//   M[row, p] = sum_{u=0}^{127} D2[u,row] * mask[u] * D1[u,p]
// where D1 = dct_mat(128), D2 = dct_mat(133), mask from the adaptive span.
// Rows >= 133 are zero padding. M1 uses rate_weights[0], M2 uses [1].
// ---------------------------------------------------------------------------
__global__ void prep_M(const float* __restrict__ rw,
                       float* __restrict__ M1,
                       float* __restrict__ M2) {
    int b   = blockIdx.x;        // 0..287
    int m   = b / NP;            // 0 -> M1 (vertical), 1 -> M2 (horizontal)
    int row = b - m * NP;        // 0..143 (output index i or j)
    int p   = threadIdx.x;       // 0..127 (input index)
    float* M = (m == 0) ? M1 : M2;

    float val = 0.0f;
    if (row < NH) {
        float r = rw[m];
        // min_allowed = max((MIN_SHAPE - SMOOTH)/cur, MIN_RATE) ; max = 2
        float minr = fmaxf((1.0f - 4.0f) / 128.0f, 0.0f);
        r = fminf(fmaxf(r, minr), 2.0f);
        float crop = 128.0f * r;

        const float c1  = (float)(M_PI / 256.0);   // D1 phase: pi*m/256, period 512
        const float c2  = (float)(M_PI / 266.0);   // D2 phase: pi*m/266, period 532
        const float s1n = 0.125f;                  // sqrt(2/128)
        const float s10 = 0.08838834764831844f;    // s1n / sqrt(2)
        const float s2n = 0.12262786485246718f;    // sqrt(2/133)
        const float s20 = 0.08671099951921386f;    // s2n / sqrt(2)

        int tp = 2 * p + 1;
        int ti = 2 * row + 1;
        float acc = 0.0f;
        for (int u = 0; u < 128; ++u) {
            float mask = fminf(fmaxf((4.0f + crop - (float)u) * 0.25f, 0.0f), 1.0f);
            int a1 = (tp * u) & 511;
            int a2 = (ti * u) % 532;
            float d1 = cosf((float)a1 * c1) * ((u == 0) ? s10 : s1n);
            float d2 = cosf((float)a2 * c2) * ((u == 0) ? s20 : s2n);
            acc = fmaf(d1 * mask, d2, acc);
        }
        val = acc;
    }
    M[row * 128 + p] = val;
}

// ---------------------------------------------------------------------------
// dct_resize: one block per (b,c) slice.
//   Phase A: Zt[j][p] = sum_q X[p][q] * M2[j][q]   (bf16 in LDS)
//   Phase B: out[i][j] = sum_p M1[i][p] * Zt[j][p]
// ---------------------------------------------------------------------------
__global__ __launch_bounds__(256, 2) void dct_resize(
        const float* __restrict__ x,
        const float* __restrict__ M1,
        const float* __restrict__ M2,
        float* __restrict__ out) {
    __shared__ float          Xp[32][132];    // 16.9 KB, stride 33x16B (bank-safe)
    __shared__ __hip_bfloat16 Zt[144][136];   // 39.2 KB, stride 17x16B (bank-safe)

    const int tid   = threadIdx.x;
    const int slice = blockIdx.x;
    const float* xs = x + (size_t)slice * (128 * 128);
    float*       os = out + (size_t)slice * (NH * NH);

    const int lg = tid >> 4;   // 0..15
    const int ll = tid & 15;   // 0..15

    // ---------------- Phase A ----------------
    for (int panel = 0; panel < 4; ++panel) {
        // cooperative load of 32 x-rows into LDS (float4, coalesced)
        #pragma unroll
        for (int k = 0; k < 4; ++k) {
            int f   = tid + k * 256;     // 0..1023
            int row = f >> 5;            // 0..31
            int c4  = f & 31;            // 0..31
            float4 v = ((const float4*)(xs + (size_t)(panel * 32 + row) * 128))[c4];
            *(float4*)&Xp[row][c4 * 4] = v;
        }
        __syncthreads();

        float acc[9][2];
        #pragma unroll
        for (int jj = 0; jj < 9; ++jj) { acc[jj][0] = 0.f; acc[jj][1] = 0.f; }

        for (int q4 = 0; q4 < 32; ++q4) {
            const float4 xv0 = *(const float4*)&Xp[ll][q4 * 4];
            const float4 xv1 = *(const float4*)&Xp[ll + 16][q4 * 4];
            #pragma unroll
            for (int jj = 0; jj < 9; ++jj) {
                const int j = lg + 16 * jj;                     // 0..143
                const float4 mv = ((const float4*)(M2 + j * 128))[q4];
                acc[jj][0] = fmaf(mv.x, xv0.x, acc[jj][0]);
                acc[jj][0] = fmaf(mv.y, xv0.y, acc[jj][0]);
                acc[jj][0] = fmaf(mv.z, xv0.z, acc[jj][0]);
                acc[jj][0] = fmaf(mv.w, xv0.w, acc[jj][0]);
                acc[jj][1] = fmaf(mv.x, xv1.x, acc[jj][1]);
                acc[jj][1] = fmaf(mv.y, xv1.y, acc[jj][1]);
                acc[jj][1] = fmaf(mv.z, xv1.z, acc[jj][1]);
                acc[jj][1] = fmaf(mv.w, xv1.w, acc[jj][1]);
            }
        }

        #pragma unroll
        for (int jj = 0; jj < 9; ++jj) {
            const int j = lg + 16 * jj;
            const int p0 = panel * 32 + ll;
            Zt[j][p0]      = __float2bfloat16(acc[jj][0]);
            Zt[j][p0 + 16] = __float2bfloat16(acc[jj][1]);
        }
        __syncthreads();
    }

    // ---------------- Phase B ----------------
    float acc3[9][9];
    #pragma unroll
    for (int ii = 0; ii < 9; ++ii)
        #pragma unroll
        for (int jj = 0; jj < 9; ++jj) acc3[ii][jj] = 0.f;

    for (int p8 = 0; p8 < 16; ++p8) {
        float zf[9][8];
        #pragma unroll
        for (int jj = 0; jj < 9; ++jj) {
            const int j = ll + 16 * jj;
            const int4 zv = *(const int4*)&Zt[j][p8 * 8];
            const unsigned ux = (unsigned)zv.x, uy = (unsigned)zv.y;
            const unsigned uz = (unsigned)zv.z, uw = (unsigned)zv.w;
            zf[jj][0] = __uint_as_float(ux << 16);
            zf[jj][1] = __uint_as_float(ux & 0xffff0000u);
            zf[jj][2] = __uint_as_float(uy << 16);
            zf[jj][3] = __uint_as_float(uy & 0xffff0000u);
            zf[jj][4] = __uint_as_float(uz << 16);
            zf[jj][5] = __uint_as_float(uz & 0xffff0000u);
            zf[jj][6] = __uint_as_float(uw << 16);
            zf[jj][7] = __uint_as_float(uw & 0xffff0000u);
        }
        #pragma unroll
        for (int ii = 0; ii < 9; ++ii) {
            const int i = lg + 16 * ii;                         // broadcast across 16 lanes
            const float4 a0 = ((const float4*)(M1 + i * 128))[p8 * 2];
            const float4 a1 = ((const float4*)(M1 + i * 128))[p8 * 2 + 1];
            #pragma unroll
            for (int jj = 0; jj < 9; ++jj) {
                float s = acc3[ii][jj];
                s = fmaf(a0.x, zf[jj][0], s);
                s = fmaf(a0.y, zf[jj][1], s);
                s = fmaf(a0.z, zf[jj][2], s);
                s = fmaf(a0.w, zf[jj][3], s);
                s = fmaf(a1.x, zf[jj][4], s);
                s = fmaf(a1.y, zf[jj][5], s);
                s = fmaf(a1.z, zf[jj][6], s);
                s = fmaf(a1.w, zf[jj][7], s);
                acc3[ii][jj] = s;
            }
        }
    }

    // ---------------- write out (crop padding) ----------------
    #pragma unroll
    for (int ii = 0; ii < 9; ++ii) {
        const int i = lg + 16 * ii;
        if (i < NH) {
            #pragma unroll
            for (int jj = 0; jj < 9; ++jj) {
                const int j = ll + 16 * jj;
                if (j < NH) os[(size_t)i * NH + j] = acc3[ii][jj];
            }
        }
    }
}

extern "C" void kernel_launch(void* const* d_in, const int* in_sizes, int n_in,
                              void* d_out, int out_size, void* d_ws, size_t ws_size,
                              hipStream_t stream) {
    const float* x  = (const float*)d_in[0];
    const float* rw = (const float*)d_in[1];
    float* outp = (float*)d_out;
    float* M1 = (float*)d_ws;            // 144*128 fp32
    float* M2 = M1 + NP * 128;           // 144*128 fp32  (total 147456 B of ws)

    prep_M<<<dim3(2 * NP), dim3(128), 0, stream>>>(rw, M1, M2);
    dct_resize<<<dim3(NSLICE), dim3(256), 0, stream>>>(x, M1, M2, outp);
}

// Round 2
// 197.098 us; speedup vs baseline: 2.4714x; 2.4714x over previous
//
#include <hip/hip_runtime.h>
#include <hip/hip_bf16.h>
#include <math.h>

#define NSLICE 2048
#define NH 133     // output spatial size (int(128*1+4)+1)
#define NP 144     // padded to 9 tiles of 16

typedef __attribute__((ext_vector_type(8))) short bf16x8;   // 8 bf16 = 4 VGPRs
typedef __attribute__((ext_vector_type(4))) float f32x4;

__device__ __forceinline__ unsigned short f2bf(float f) {
    __hip_bfloat16 h = __float2bfloat16(f);   // round-to-nearest-even
    union { __hip_bfloat16 b; unsigned short u; } c; c.b = h; return c.u;
}

// ---------------------------------------------------------------------------
// prep_M: combined (IDCT * mask * DCT) matrices, bf16, in workspace.
//   M[row, p] = sum_{u=0}^{127} D2[u,row] * mask[u] * D1[u,p]
// Rows >= 133 are zero padding. M1 uses rate_weights[0], M2 uses [1].
// ---------------------------------------------------------------------------
__global__ void prep_M(const float* __restrict__ rw,
                       unsigned short* __restrict__ M1,
                       unsigned short* __restrict__ M2) {
    int b   = blockIdx.x;        // 0..287
    int m   = b / NP;            // 0 -> M1 (vertical), 1 -> M2 (horizontal)
    int row = b - m * NP;        // 0..143 (output index i or j)
    int p   = threadIdx.x;       // 0..127 (input index)
    unsigned short* M = (m == 0) ? M1 : M2;

    float val = 0.0f;
    if (row < NH) {
        float r = rw[m];
        float minr = fmaxf((1.0f - 4.0f) / 128.0f, 0.0f);
        r = fminf(fmaxf(r, minr), 2.0f);
        float crop = 128.0f * r;

        const float c1  = (float)(M_PI / 256.0);   // D1 phase period 512
        const float c2  = (float)(M_PI / 266.0);   // D2 phase period 532
        const float s1n = 0.125f;                  // sqrt(2/128)
        const float s10 = 0.08838834764831844f;
        const float s2n = 0.12262786485246718f;    // sqrt(2/133)
        const float s20 = 0.08671099951921386f;

        int tp = 2 * p + 1;
        int ti = 2 * row + 1;
        float acc = 0.0f;
        for (int u = 0; u < 128; ++u) {
            float mask = fminf(fmaxf((4.0f + crop - (float)u) * 0.25f, 0.0f), 1.0f);
            int a1 = (tp * u) & 511;
            int a2 = (ti * u) % 532;
            float d1 = cosf((float)a1 * c1) * ((u == 0) ? s10 : s1n);
            float d2 = cosf((float)a2 * c2) * ((u == 0) ? s20 : s2n);
            acc = fmaf(d1 * mask, d2, acc);
        }
        val = acc;
    }
    M[row * 128 + p] = f2bf(val);
}

// ---------------------------------------------------------------------------
// dct_resize: one 512-thread block (8 waves) per (b,c) slice.
//   stage X -> bf16 LDS (converted in flight)
//   Stage A (MFMA): Tt[j][p] = sum_q X[p][q] * M2[j][q]      (bf16 in LDS)
//   Stage B (MFMA): out[i][j] = sum_p M1[i][p] * Tt[j][p]
// M1/M2 fragments are read from global (36 KB each, L2-hot).
// ---------------------------------------------------------------------------
__global__ __launch_bounds__(512, 4) void dct_resize(
        const float* __restrict__ x,
        const unsigned short* __restrict__ M1,
        const unsigned short* __restrict__ M2,
        float* __restrict__ out) {
    __shared__ unsigned short Xs[128][136];   // 34.0 KB, row stride 17x16B
    __shared__ unsigned short Tt[144][136];   // 39.2 KB, row stride 17x16B

    const int tid  = threadIdx.x;
    const int w    = tid >> 6;      // wave 0..7
    const int lane = tid & 63;
    const int r    = lane & 15;     // fragment row/col index
    const int g    = lane >> 4;     // k-group 0..3

    const float* xs = x + (size_t)blockIdx.x * (128 * 128);
    float*       os = out + (size_t)blockIdx.x * (NH * NH);

    // ---- stage X into LDS as bf16 (coalesced float4 reads) ----
    #pragma unroll
    for (int k = 0; k < 8; ++k) {
        int f   = tid + k * 512;      // 0..4095
        int row = f >> 5;             // 0..127
        int c4  = f & 31;             // float4 column
        float4 v = ((const float4*)(xs + (size_t)row * 128))[c4];
        uint2 pkt;
        pkt.x = (unsigned)f2bf(v.x) | ((unsigned)f2bf(v.y) << 16);
        pkt.y = (unsigned)f2bf(v.z) | ((unsigned)f2bf(v.w) << 16);
        *(uint2*)&Xs[row][c4 * 4] = pkt;
    }
    __syncthreads();

    // ---- Stage A: wave w owns p-tile w (rows p0..p0+15) ----
    {
        const int p0 = w * 16;
        bf16x8 a[4];
        #pragma unroll
        for (int kk = 0; kk < 4; ++kk)
            a[kk] = *(const bf16x8*)&Xs[p0 + r][kk * 32 + g * 8];

        for (int j9 = 0; j9 < 9; ++j9) {
            const int j0 = j9 * 16;
            f32x4 acc = {0.f, 0.f, 0.f, 0.f};
            #pragma unroll
            for (int kk = 0; kk < 4; ++kk) {
                bf16x8 b = *(const bf16x8*)(M2 + (size_t)(j0 + r) * 128 + kk * 32 + g * 8);
                acc = __builtin_amdgcn_mfma_f32_16x16x32_bf16(a[kk], b, acc, 0, 0, 0);
            }
            // D[p][j]: row p = g*4+q, col j = r  ->  Tt[j][p], 4 consecutive p
            uint2 pkt;
            pkt.x = (unsigned)f2bf(acc[0]) | ((unsigned)f2bf(acc[1]) << 16);
            pkt.y = (unsigned)f2bf(acc[2]) | ((unsigned)f2bf(acc[3]) << 16);
            *(uint2*)&Tt[j0 + r][p0 + g * 4] = pkt;
        }
    }
    __syncthreads();

    // ---- Stage B: 81 tiles distributed over 8 waves ----
    for (int t = w; t < 81; t += 8) {
        const int i0 = (t / 9) * 16;
        const int j0 = (t % 9) * 16;
        f32x4 acc = {0.f, 0.f, 0.f, 0.f};
        #pragma unroll
        for (int kk = 0; kk < 4; ++kk) {
            bf16x8 a = *(const bf16x8*)(M1 + (size_t)(i0 + r) * 128 + kk * 32 + g * 8);
            bf16x8 b = *(const bf16x8*)&Tt[j0 + r][kk * 32 + g * 8];
            acc = __builtin_amdgcn_mfma_f32_16x16x32_bf16(a, b, acc, 0, 0, 0);
        }
        const int j = j0 + r;
        if (j < NH) {
            #pragma unroll
            for (int q = 0; q < 4; ++q) {
                const int i = i0 + g * 4 + q;
                if (i < NH) os[(size_t)i * NH + j] = acc[q];
            }
        }
    }
}

extern "C" void kernel_launch(void* const* d_in, const int* in_sizes, int n_in,
                              void* d_out, int out_size, void* d_ws, size_t ws_size,
                              hipStream_t stream) {
    const float* x  = (const float*)d_in[0];
    const float* rw = (const float*)d_in[1];
    float* outp = (float*)d_out;
    unsigned short* M1 = (unsigned short*)d_ws;     // 144*128 bf16
    unsigned short* M2 = M1 + NP * 128;             // 144*128 bf16 (73.7 KB total)

    prep_M<<<dim3(2 * NP), dim3(128), 0, stream>>>(rw, M1, M2);
    dct_resize<<<dim3(NSLICE), dim3(512), 0, stream>>>(x, M1, M2, outp);
}

// Round 3
// 113.274 us; speedup vs baseline: 4.3003x; 1.7400x over previous
//
#include <hip/hip_runtime.h>
#include <hip/hip_bf16.h>
#include <math.h>

#define NSLICE 2048
#define NH 133     // output spatial size (int(128*1+4)+1)
#define NP 144     // padded to 9 tiles of 16
#define NT 576     // 9 waves per block

typedef __attribute__((ext_vector_type(8))) short bf16x8;   // 8 bf16 = 4 VGPRs
typedef __attribute__((ext_vector_type(4))) float f32x4;

__device__ __forceinline__ unsigned f2bf(float f) {
    __hip_bfloat16 h = __float2bfloat16(f);   // round-to-nearest-even
    union { __hip_bfloat16 b; unsigned short u; } c; c.b = h; return (unsigned)c.u;
}

// ---------------------------------------------------------------------------
// prep_M: combined (IDCT * mask * DCT) matrices, bf16, in workspace.
//   M[row, p] = sum_{u=0}^{127} D2[u,row] * mask[u] * D1[u,p]
// Rows >= 133 are zero padding. M1 uses rate_weights[0], M2 uses [1].
// ---------------------------------------------------------------------------
__global__ void prep_M(const float* __restrict__ rw,
                       unsigned short* __restrict__ M1,
                       unsigned short* __restrict__ M2) {
    int b   = blockIdx.x;        // 0..287
    int m   = b / NP;            // 0 -> M1 (vertical), 1 -> M2 (horizontal)
    int row = b - m * NP;        // 0..143 (output index i or j)
    int p   = threadIdx.x;       // 0..127 (input index)
    unsigned short* M = (m == 0) ? M1 : M2;

    float val = 0.0f;
    if (row < NH) {
        float r = rw[m];
        float minr = fmaxf((1.0f - 4.0f) / 128.0f, 0.0f);
        r = fminf(fmaxf(r, minr), 2.0f);
        float crop = 128.0f * r;

        const float c1  = (float)(M_PI / 256.0);   // D1 phase period 512
        const float c2  = (float)(M_PI / 266.0);   // D2 phase period 532
        const float s1n = 0.125f;                  // sqrt(2/128)
        const float s10 = 0.08838834764831844f;
        const float s2n = 0.12262786485246718f;    // sqrt(2/133)
        const float s20 = 0.08671099951921386f;

        int tp = 2 * p + 1;
        int ti = 2 * row + 1;
        float acc = 0.0f;
        for (int u = 0; u < 128; ++u) {
            float mask = fminf(fmaxf((4.0f + crop - (float)u) * 0.25f, 0.0f), 1.0f);
            int a1 = (tp * u) & 511;
            int a2 = (ti * u) % 532;
            float d1 = cosf((float)a1 * c1) * ((u == 0) ? s10 : s1n);
            float d2 = cosf((float)a2 * c2) * ((u == 0) ? s20 : s2n);
            acc = fmaf(d1 * mask, d2, acc);
        }
        val = acc;
    }
    M[row * 128 + p] = (unsigned short)f2bf(val);
}

// ---------------------------------------------------------------------------
// dct_resize: one 576-thread block (9 waves) per (b,c) slice.
//   wave w preloads its M2 fragments (j-tile w) and M1 fragments (i-tile w)
//   into registers BEFORE the staging barrier (latency hidden under X loads).
//   Stage A: wave w computes Tt[j0..j0+15][:] iterating the 8 p-tiles of X.
//   Stage B: wave w computes out rows i0..i0+15 iterating the 9 j-tiles.
// ---------------------------------------------------------------------------
__global__ __launch_bounds__(NT, 4) void dct_resize(
        const float* __restrict__ x,
        const unsigned short* __restrict__ M1,
        const unsigned short* __restrict__ M2,
        float* __restrict__ out) {
    __shared__ unsigned short Xs[128][136];   // 34.0 KB, row stride 17x16B
    __shared__ unsigned short Tt[144][136];   // 38.3 KB, row stride 17x16B

    const int tid  = threadIdx.x;
    const int w    = tid >> 6;      // wave 0..8
    const int lane = tid & 63;
    const int r    = lane & 15;     // fragment row/col index
    const int g    = lane >> 4;     // k-group 0..3

    const float* xs = x + (size_t)blockIdx.x * (128 * 128);
    float*       os = out + (size_t)blockIdx.x * (NH * NH);

    const int j0 = w * 16;          // stage A: this wave's j-tile
    const int i0 = w * 16;          // stage B: this wave's i-tile

    // ---- preload loop-invariant matrix fragments (L2-hot, once per wave) ----
    bf16x8 bm2[4], am1[4];
    #pragma unroll
    for (int kk = 0; kk < 4; ++kk) {
        bm2[kk] = *(const bf16x8*)(M2 + (size_t)(j0 + r) * 128 + kk * 32 + g * 8);
        am1[kk] = *(const bf16x8*)(M1 + (size_t)(i0 + r) * 128 + kk * 32 + g * 8);
    }

    // ---- stage X into LDS as bf16 (coalesced float4 reads) ----
    for (int f = tid; f < 4096; f += NT) {
        int row = f >> 5;             // 0..127
        int c4  = f & 31;             // float4 column
        float4 v = ((const float4*)(xs + (size_t)row * 128))[c4];
        uint2 pkt;
        pkt.x = f2bf(v.x) | (f2bf(v.y) << 16);
        pkt.y = f2bf(v.z) | (f2bf(v.w) << 16);
        *(uint2*)&Xs[row][c4 * 4] = pkt;
    }
    __syncthreads();

    // ---- Stage A: Tt[j][p] = sum_q X[p][q] * M2[j][q] ----
    #pragma unroll
    for (int pt = 0; pt < 8; ++pt) {
        f32x4 acc = {0.f, 0.f, 0.f, 0.f};
        #pragma unroll
        for (int kk = 0; kk < 4; ++kk) {
            bf16x8 a = *(const bf16x8*)&Xs[pt * 16 + r][kk * 32 + g * 8];
            acc = __builtin_amdgcn_mfma_f32_16x16x32_bf16(a, bm2[kk], acc, 0, 0, 0);
        }
        // D[p][j]: col j = r, row p = g*4+q  ->  Tt[j0+r][pt*16+g*4 ..]
        uint2 pkt;
        pkt.x = f2bf(acc[0]) | (f2bf(acc[1]) << 16);
        pkt.y = f2bf(acc[2]) | (f2bf(acc[3]) << 16);
        *(uint2*)&Tt[j0 + r][pt * 16 + g * 4] = pkt;
    }
    __syncthreads();

    // ---- Stage B: out[i][j] = sum_p M1[i][p] * Tt[j][p] ----
    #pragma unroll
    for (int jt = 0; jt < 9; ++jt) {
        f32x4 acc = {0.f, 0.f, 0.f, 0.f};
        #pragma unroll
        for (int kk = 0; kk < 4; ++kk) {
            bf16x8 b = *(const bf16x8*)&Tt[jt * 16 + r][kk * 32 + g * 8];
            acc = __builtin_amdgcn_mfma_f32_16x16x32_bf16(am1[kk], b, acc, 0, 0, 0);
        }
        const int j = jt * 16 + r;
        if (j < NH) {
            #pragma unroll
            for (int q = 0; q < 4; ++q) {
                const int i = i0 + g * 4 + q;
                if (i < NH) os[(size_t)i * NH + j] = acc[q];
            }
        }
    }
}

extern "C" void kernel_launch(void* const* d_in, const int* in_sizes, int n_in,
                              void* d_out, int out_size, void* d_ws, size_t ws_size,
                              hipStream_t stream) {
    const float* x  = (const float*)d_in[0];
    const float* rw = (const float*)d_in[1];
    float* outp = (float*)d_out;
    unsigned short* M1 = (unsigned short*)d_ws;     // 144*128 bf16
    unsigned short* M2 = M1 + NP * 128;             // 144*128 bf16 (73.7 KB total)

    prep_M<<<dim3(2 * NP), dim3(128), 0, stream>>>(rw, M1, M2);
    dct_resize<<<dim3(NSLICE), dim3(NT), 0, stream>>>(x, M1, M2, outp);
}